// Round 6
// baseline (238.102 us; speedup 1.0000x reference)
//
#include <hip/hip_runtime.h>

// LSTM: B=4096, T=256, I=8, H=32, O=1, fp32 in/out, bf16 MFMA compute.
// R6: FULLY REGISTER-RESIDENT RECURRENCE — one wave owns 16 batch rows and
// the entire hidden state; no LDS, no barriers, no cross-lane ops in the loop.
// 256 blocks x 64 threads (1 wave each, 256 independent waves).
//
// Per MFMA k (k=0..7), weights are the FIRST operand with row permutation
//   fr -> n = 32*(fr&3) + 8*(fr>>2) + k,
// so lane (q,L) reg r of D_k = gate r at (m=L, j=8q+k). Over k=0..7 a lane
// accumulates h(m=L, j=8q+0..7) — exactly the B-operand fragment
// B[m=L][kdim=8q+j'] the next step's recurrence MFMA needs. The loop is:
//   acc_k = mfma(whh_k, hfrag, zx_k)        (8 on-chain MFMAs)
//   zx_k  = mfma(wih_k, xfrag(t+1), bias_k) (8 off-chain)
//   act -> c_k, h_k -> pack hfrag           (64 trans, in-register)
// x comes from a depth-4 register prefetch ring (~5 steps of slack; no
// barrier ever drains vmcnt). Gate-g rows pre-scaled by 2*log2e (others
// log2e): 5 exp2 + 3 rcp per (m,j).

#define T_LEN 256
#define LOG2E 1.4426950408889634f

typedef short bf16x8 __attribute__((ext_vector_type(8)));
typedef float f32x4  __attribute__((ext_vector_type(4)));
typedef unsigned u32x4 __attribute__((ext_vector_type(4)));

static __device__ inline short f2bf_rne(float f) {           // one-time (weights)
    union { float f; unsigned u; } v; v.f = f;
    unsigned u = v.u;
    return (short)((u + 0x7FFFu + ((u >> 16) & 1u)) >> 16);
}
static __device__ inline unsigned pack_bf2(float a, float b) {  // low=a, high=b
    union { float f; unsigned u; } x, y; x.f = a; y.f = b;
    return ((x.u + 0x8000u) >> 16) | ((y.u + 0x8000u) & 0xFFFF0000u);
}

__global__ __launch_bounds__(64, 1) void lstm_kernel(
    const float* __restrict__ x, const float* __restrict__ W_ih,
    const float* __restrict__ W_hh, const float* __restrict__ b_ih,
    const float* __restrict__ b_hh, const float* __restrict__ W_out,
    const float* __restrict__ b_out, float* __restrict__ out)
{
    const int lane = threadIdx.x;     // single wave per block
    const int L    = lane & 15;       // batch row within tile / operand row
    const int q    = lane >> 4;       // quad
    const int row0 = blockIdx.x * 16;

    // ---- one-time: weight fragments for all 8 MFMAs ----
    // A-frag layout: [row = L][kdim = 8q + j]. Row L of MFMA k holds W row
    // n = 32*(L&3) + 8*(L>>2) + k, scaled by log2e (2*log2e for gate g).
    const int   nbase = 32 * (L & 3) + 8 * (L >> 2);
    const float sc    = ((L & 3) == 2 ? 2.f * LOG2E : LOG2E);
    bf16x8 whh[8], wih[8];
    f32x4  bias[8];
#pragma unroll
    for (int k = 0; k < 8; ++k) {
        const int n = nbase + k;
        const float* src = W_hh + n * 32 + q * 8;
        bf16x8 fr;
#pragma unroll
        for (int j = 0; j < 8; ++j) fr[j] = f2bf_rne(src[j] * sc);
        whh[k] = fr;
        bf16x8 gr = (bf16x8){0,0,0,0,0,0,0,0};
        if (q == 0) {                               // only kdim 0..7 exist (I=8)
            const float* s2 = W_ih + n * 8;
#pragma unroll
            for (int j = 0; j < 8; ++j) gr[j] = f2bf_rne(s2[j] * sc);
        }
        wih[k] = gr;
        // bias in C-layout: reg r -> (gate r, j = 8q + k): n_r = 32r + 8q + k
        f32x4 bb;
#pragma unroll
        for (int r = 0; r < 4; ++r) {
            const int   nr = 32 * r + 8 * q + k;
            const float sr = (r == 2 ? 2.f * LOG2E : LOG2E);
            bb[r] = (b_ih[nr] + b_hh[nr]) * sr;
        }
        bias[k] = bb;
    }

    // ---- x prefetch ring, depth 4: slot s holds x(t), t === s (mod 4) ----
    // every lane loads its row's x(t)[0..7] (32 B); q>0 duplicates hit L1.
    // q>0 lanes' B-rows multiply the zeroed kdim>=8 wih rows -> contribute 0,
    // but values must be finite, so all lanes carry real x.
    const float4* xv = (const float4*)x;
    const size_t  xb = (size_t)(row0 + L) * (T_LEN * 8 / 4);
    float4 r0[4], r1[4];
    const float4 a0 = xv[xb + 0], b0 = xv[xb + 1];   // x(0), consumed now
    r0[1] = xv[xb + 2]; r1[1] = xv[xb + 3];          // x(1)
    r0[2] = xv[xb + 4]; r1[2] = xv[xb + 5];          // x(2)
    r0[3] = xv[xb + 6]; r1[3] = xv[xb + 7];          // x(3)
    r0[0] = xv[xb + 8]; r1[0] = xv[xb + 9];          // x(4) -> slot 0

    // zx(0) from x(0)
    f32x4 zx[8];
    {
        u32x4 u;
        u[0] = pack_bf2(a0.x, a0.y); u[1] = pack_bf2(a0.z, a0.w);
        u[2] = pack_bf2(b0.x, b0.y); u[3] = pack_bf2(b0.z, b0.w);
        const bf16x8 xf0 = *(const bf16x8*)&u;
#pragma unroll
        for (int k = 0; k < 8; ++k)
            zx[k] = __builtin_amdgcn_mfma_f32_16x16x32_bf16(wih[k], xf0, bias[k], 0, 0, 0);
    }

    bf16x8 hfrag = (bf16x8){0,0,0,0,0,0,0,0};        // h(0) = 0
    float c[8]  = {0,0,0,0,0,0,0,0};
    float hh[8] = {0,0,0,0,0,0,0,0};

#pragma unroll 4
    for (int t = 0; t < T_LEN; ++t) {
        // the only MFMAs on the recurrence chain (8, independent given hfrag)
        f32x4 acc[8];
#pragma unroll
        for (int k = 0; k < 8; ++k)
            acc[k] = __builtin_amdgcn_mfma_f32_16x16x32_bf16(whh[k], hfrag, zx[k], 0, 0, 0);

        // xfrag(t+1) from ring slot (t+1)&3; refill slot with x(t+5)
        {
            const int s = (t + 1) & 3;
            const float4 a = r0[s], b = r1[s];
            u32x4 u;
            u[0] = pack_bf2(a.x, a.y); u[1] = pack_bf2(a.z, a.w);
            u[2] = pack_bf2(b.x, b.y); u[3] = pack_bf2(b.z, b.w);
            const bf16x8 xf = *(const bf16x8*)&u;
            int tn = t + 5; if (tn >= T_LEN) tn = T_LEN - 1;
            r0[s] = xv[xb + (size_t)tn * 2];
            r1[s] = xv[xb + (size_t)tn * 2 + 1];
#pragma unroll
            for (int k = 0; k < 8; ++k)
                zx[k] = __builtin_amdgcn_mfma_f32_16x16x32_bf16(wih[k], xf, bias[k], 0, 0, 0);
        }

        // activations: regs r = (i, f, g2, o), g rows pre-doubled.
        // sig(a)*tanh(b) = (1-eb)*rcp((1+ea)(1+eb)); only the c-exp needs a clamp.
#pragma unroll
        for (int k = 0; k < 8; ++k) {
            const float ei = __builtin_amdgcn_exp2f(-acc[k][0]);
            const float ef = __builtin_amdgcn_exp2f(-acc[k][1]);
            const float eg = __builtin_amdgcn_exp2f(-acc[k][2]);
            const float eo = __builtin_amdgcn_exp2f(-acc[k][3]);
            const float fv = __builtin_amdgcn_rcpf(1.f + ef);
            const float ig = (1.f - eg) * __builtin_amdgcn_rcpf((1.f + ei) * (1.f + eg));
            c[k] = fmaf(fv, c[k], ig);
            const float ec = __builtin_amdgcn_exp2f(fminf(c[k] * (-2.f * LOG2E), 40.f));
            hh[k] = (1.f - ec) * __builtin_amdgcn_rcpf((1.f + eo) * (1.f + ec));
        }

        // repack h(t+1) into the next B-fragment: element j' = h(j=8q+j')
        {
            u32x4 hu;
            hu[0] = pack_bf2(hh[0], hh[1]); hu[1] = pack_bf2(hh[2], hh[3]);
            hu[2] = pack_bf2(hh[4], hh[5]); hu[3] = pack_bf2(hh[6], hh[7]);
            hfrag = *(const bf16x8*)&hu;
        }
    }

    // epilogue: out[b] = sum_j h(b,j) W_out[j] + b_out; lane (q,L) holds
    // j = 8q..8q+7 (float, pre-bf16-rounding). Reduce across quads via shfl.
    float s = 0.f;
#pragma unroll
    for (int k = 0; k < 8; ++k) s += hh[k] * W_out[8 * q + k];
    s += __shfl_xor(s, 16, 64);
    s += __shfl_xor(s, 32, 64);
    if (lane < 16) out[row0 + L] = s + b_out[0];
}

extern "C" void kernel_launch(void* const* d_in, const int* in_sizes, int n_in,
                              void* d_out, int out_size, void* d_ws, size_t ws_size,
                              hipStream_t stream) {
    const float* x     = (const float*)d_in[0];
    const float* W_ih  = (const float*)d_in[1];
    const float* W_hh  = (const float*)d_in[2];
    const float* b_ih  = (const float*)d_in[3];
    const float* b_hh  = (const float*)d_in[4];
    const float* W_out = (const float*)d_in[5];
    const float* b_out = (const float*)d_in[6];
    float* out = (float*)d_out;

    const int B = in_sizes[0] / (T_LEN * 8);  // 4096
    const int tiles = B / 16;                 // 256 waves, one per CU
    lstm_kernel<<<tiles, 64, 0, stream>>>(x, W_ih, W_hh, b_ih, b_hh, W_out, b_out, out);
}

// Round 7
// 141.366 us; speedup vs baseline: 1.6843x; 1.6843x over previous
//
#include <hip/hip_runtime.h>

// LSTM: B=4096, T=256, I=8, H=32, O=1, fp32 in/out, bf16 MFMA compute.
// R7 = R5 structure + 8-way j-split (512 threads, 2 waves/SIMD):
// 256 blocks (1/CU) x 8 waves. Block owns 16 batch rows; wave w owns hidden
// j = 4w + q (ONE (m,j) value per lane) via weight-row permutation
//   fr -> n = 32*(fr&3) + 4w + (fr>>2)   (weights are the MFMA FIRST operand)
// so lane (q,L) accum reg r = gate r at (m=L, j=4w+q): c/h update fully
// in-register, 8 trans/lane/step. Two waves per SIMD interleave issue inside
// each other's act-chain/ds_read stalls (the R5 single-wave/SIMD exposure).
// x staged in LDS as bf16 in two 128-step chunks (zero global ops in the
// steady-state loop -> barrier drains only lgkmcnt). Gate-g rows pre-scaled
// by 2*log2e (others log2e): 5 exp2 + 3 rcp per value.

#define T_LEN   256
#define HALF_T  128
#define XSTRIDE 130   // shorts per timestep row (16 L x 8 bf16 + 2 pad)
#define LOG2E   1.4426950408889634f

typedef short bf16x8 __attribute__((ext_vector_type(8)));
typedef float f32x4  __attribute__((ext_vector_type(4)));
typedef unsigned u32x4 __attribute__((ext_vector_type(4)));

static __device__ inline short f2bf_rne(float f) {          // one-time (weights)
    union { float f; unsigned u; } v; v.f = f;
    unsigned u = v.u;
    return (short)((u + 0x7FFFu + ((u >> 16) & 1u)) >> 16);
}
static __device__ inline short f2bf_fast(float f) {         // round-half-up
    union { float f; unsigned u; } v; v.f = f;
    return (short)((v.u + 0x8000u) >> 16);
}
static __device__ inline unsigned pack_bf2(float a, float b) {  // low=a, high=b
    union { float f; unsigned u; } x, y; x.f = a; y.f = b;
    return ((x.u + 0x8000u) >> 16) | ((y.u + 0x8000u) & 0xFFFF0000u);
}
static __device__ inline float bf2f(short s) {
    union { unsigned u; float f; } v;
    v.u = ((unsigned)(unsigned short)s) << 16;
    return v.f;
}

__global__ __launch_bounds__(512, 2) void lstm_kernel(
    const float* __restrict__ x, const float* __restrict__ W_ih,
    const float* __restrict__ W_hh, const float* __restrict__ b_ih,
    const float* __restrict__ b_hh, const float* __restrict__ W_out,
    const float* __restrict__ b_out, float* __restrict__ out)
{
    // x chunk: [t_local(0..127)][L(0..15)][8] bf16 (conflict-free: dword
    // stride 65/t, 4/L; loop reads are 4-lane broadcasts of 16 addresses)
    __shared__ __attribute__((aligned(16))) short xl[HALF_T * XSTRIDE];
    // h double buffer: [buf][m(0..15)][k(0..31)] bf16, row stride 40 shorts
    __shared__ __attribute__((aligned(16))) short h_lds[2][16 * 40];

    const int tid  = threadIdx.x;
    const int w    = tid >> 6;        // wave 0..7 -> owns j = 4w + q
    const int lane = tid & 63;
    const int L    = lane & 15;       // batch row within tile / frag row
    const int q    = lane >> 4;       // quad
    const int row0 = blockIdx.x * 16;
    const float4* xv = (const float4*)x;

    // ---- one-time: weight fragments (FIRST-operand layout [row=L][k=8q+j]) ----
    // row fr=L holds W row n = 32*(L&3) + 4w + (L>>2); gate = L&3,
    // scaled by log2e (gate-g rows: 2*log2e, folding tanh's factor 2).
    const int   n  = 32 * (L & 3) + 4 * w + (L >> 2);
    const float sc = ((L & 3) == 2 ? 2.f * LOG2E : LOG2E);
    bf16x8 whh_f, wih_f = (bf16x8){0,0,0,0,0,0,0,0};
    {
        const float* src = W_hh + n * 32 + q * 8;
#pragma unroll
        for (int j = 0; j < 8; ++j) whh_f[j] = f2bf_rne(src[j] * sc);
        if (q == 0) {                              // only k=0..7 exist (I=8)
            const float* s2 = W_ih + n * 8;
#pragma unroll
            for (int j = 0; j < 8; ++j) wih_f[j] = f2bf_rne(s2[j] * sc);
        }
    }
    // bias in C-layout: reg r -> row fr=4q+r -> n_r = 32r + 4w + q
    f32x4 bias;
#pragma unroll
    for (int r = 0; r < 4; ++r) {
        const int   nr = 32 * r + 4 * w + q;
        const float sr = (r == 2 ? 2.f * LOG2E : LOG2E);
        bias[r] = (b_ih[nr] + b_hh[nr]) * sr;
    }

    // zero h(0) buffer
    for (int i = tid; i < 16 * 40; i += 512) h_lds[0][i] = 0;

    // ---- stage chunk 0 (t in [0,128)) into xl ----
    // idx = tid + 512*it: L2 = idx>>7, tl = idx&127; 32 B/lane coalesced.
#pragma unroll
    for (int it = 0; it < 4; ++it) {
        const int idx = tid + (it << 9);
        const int L2  = idx >> 7;
        const int tl  = idx & (HALF_T - 1);
        const float4* srcp = xv + ((size_t)(row0 + L2) * T_LEN + tl) * 2;
        const float4 a = srcp[0], b = srcp[1];
        u32x4 u;
        u[0] = pack_bf2(a.x, a.y); u[1] = pack_bf2(a.z, a.w);
        u[2] = pack_bf2(b.x, b.y); u[3] = pack_bf2(b.z, b.w);
        *(u32x4*)(&xl[tl * XSTRIDE + L2 * 8]) = u;
    }
    __syncthreads();

    // zx(0) from x(0)
    f32x4 zx;
    {
        const bf16x8 xf0 = *(const bf16x8*)(&xl[L * 8]);
        zx = __builtin_amdgcn_mfma_f32_16x16x32_bf16(wih_f, xf0, bias, 0, 0, 0);
    }

    float c = 0.f;
    const int hw_off = 4 * w + q;      // this lane's j

#pragma unroll 2
    for (int t = 0; t < T_LEN; ++t) {
        if (t == HALF_T - 1) {
            // chunk-0 fully consumed (last read was x(127) during t=126).
#pragma unroll
            for (int it = 0; it < 4; ++it) {
                const int idx = tid + (it << 9);
                const int L2  = idx >> 7;
                const int tl  = idx & (HALF_T - 1);
                const float4* srcp = xv + ((size_t)(row0 + L2) * T_LEN + HALF_T + tl) * 2;
                const float4 a = srcp[0], b = srcp[1];
                u32x4 u;
                u[0] = pack_bf2(a.x, a.y); u[1] = pack_bf2(a.z, a.w);
                u[2] = pack_bf2(b.x, b.y); u[3] = pack_bf2(b.z, b.w);
                *(u32x4*)(&xl[tl * XSTRIDE + L2 * 8]) = u;
            }
            __syncthreads();   // one-time vm drain; loop stays vm-free
        }

        const int par = t & 1, nxt = par ^ 1;

        // h(t) fragment [n=L][k=8q+j]
        const bf16x8 hfrag = *(const bf16x8*)(&h_lds[par][L * 40 + q * 8]);
        // x(t+1) fragment (broadcast read; q>0 lanes hit zeroed wih rows)
        int tn = t + 1; if (tn >= T_LEN) tn = T_LEN - 1;
        const bf16x8 xfrag = *(const bf16x8*)(&xl[(tn & (HALF_T - 1)) * XSTRIDE + L * 8]);

        // recurrence MFMA (chain) + next-step zx (off-chain)
        const f32x4 acc = __builtin_amdgcn_mfma_f32_16x16x32_bf16(whh_f, hfrag, zx, 0, 0, 0);
        zx = __builtin_amdgcn_mfma_f32_16x16x32_bf16(wih_f, xfrag, bias, 0, 0, 0);

        // activation: regs r = (i, f, g2, o); g rows pre-doubled.
        // sig(a)*tanh(b) = (1-eb)*rcp((1+ea)(1+eb)); only c-exp clamped.
        {
            const float ei = __builtin_amdgcn_exp2f(-acc[0]);
            const float ef = __builtin_amdgcn_exp2f(-acc[1]);
            const float eg = __builtin_amdgcn_exp2f(-acc[2]);
            const float eo = __builtin_amdgcn_exp2f(-acc[3]);
            const float fv = __builtin_amdgcn_rcpf(1.f + ef);
            const float ig = (1.f - eg) * __builtin_amdgcn_rcpf((1.f + ei) * (1.f + eg));
            c = fmaf(fv, c, ig);
            const float ec = __builtin_amdgcn_exp2f(fminf(c * (-2.f * LOG2E), 40.f));
            const float hv = (1.f - ec) * __builtin_amdgcn_rcpf((1.f + eo) * (1.f + ec));
            h_lds[nxt][L * 40 + hw_off] = f2bf_fast(hv);
        }

        __syncthreads();   // LDS-only drain: no global ops in flight
    }

    // h(T) lives in buf[(255+1)&1] = buf[0]
    if (tid < 16) {
        float s = b_out[0];
#pragma unroll
        for (int k = 0; k < 32; ++k) s = fmaf(bf2f(h_lds[0][tid * 40 + k]), W_out[k], s);
        out[row0 + tid] = s;
    }
}

extern "C" void kernel_launch(void* const* d_in, const int* in_sizes, int n_in,
                              void* d_out, int out_size, void* d_ws, size_t ws_size,
                              hipStream_t stream) {
    const float* x     = (const float*)d_in[0];
    const float* W_ih  = (const float*)d_in[1];
    const float* W_hh  = (const float*)d_in[2];
    const float* b_ih  = (const float*)d_in[3];
    const float* b_hh  = (const float*)d_in[4];
    const float* W_out = (const float*)d_in[5];
    const float* b_out = (const float*)d_in[6];
    float* out = (float*)d_out;

    const int B = in_sizes[0] / (T_LEN * 8);  // 4096
    const int tiles = B / 16;                 // 256 blocks, one per CU
    lstm_kernel<<<tiles, 512, 0, stream>>>(x, W_ih, W_hh, b_ih, b_hh, W_out, b_out, out);
}